// Round 12
// baseline (650.427 us; speedup 1.0000x reference)
//
#include <hip/hip_runtime.h>
#include <hip/hip_bf16.h>
#include <stdint.h>

#define BATCH   16384
#define EXPERTS 8
#define IN_DIM  1024
#define OUT_DIM 1024

typedef unsigned short u16;
typedef short  bf16x8 __attribute__((ext_vector_type(8)));
typedef float  f32x4  __attribute__((ext_vector_type(4)));

__device__ __forceinline__ u16 f2bf(float f) {
  uint32_t u = __float_as_uint(f);
  u += 0x7fffu + ((u >> 16) & 1u);   // RNE
  return (u16)(u >> 16);
}

#define GLDS16(g, l)                                                      \
  __builtin_amdgcn_global_load_lds(                                       \
      (const __attribute__((address_space(1))) void*)(g),                 \
      (__attribute__((address_space(3))) void*)(l), 16, 0, 0)

#define MFMA_BF16 __builtin_amdgcn_mfma_f32_16x16x32_bf16
#define SB0 __builtin_amdgcn_sched_barrier(0)

// ---------------- kernel 1: x fp32 -> bf16 ----------------
__global__ void cvt_x(const float* __restrict__ x, u16* __restrict__ xb) {
  size_t i = ((size_t)blockIdx.x * 256 + threadIdx.x) * 4;
  float4 v = *reinterpret_cast<const float4*>(x + i);
  ushort4 o;
  o.x = f2bf(v.x); o.y = f2bf(v.y); o.z = f2bf(v.z); o.w = f2bf(v.w);
  *reinterpret_cast<ushort4*>(xb + i) = o;
}

// ------- kernel 2: W[e][i][o] fp32 -> Wbt[e][o][i] bf16 (transpose) -------
__global__ void cvt_w(const float* __restrict__ W, u16* __restrict__ wbt) {
  __shared__ u16 t[64][72];
  const int e  = blockIdx.z;
  const int i0 = blockIdx.x * 64;
  const int o0 = blockIdx.y * 64;
  const int tid = threadIdx.x;
  const int c  = (tid & 15) * 4;
  const int r_ = tid >> 4;
  const float* src = W + ((size_t)e << 20);
#pragma unroll
  for (int p = 0; p < 4; ++p) {
    int r = r_ + p * 16;
    float4 v = *reinterpret_cast<const float4*>(src + (size_t)(i0 + r) * 1024 + o0 + c);
    t[r][c + 0] = f2bf(v.x); t[r][c + 1] = f2bf(v.y);
    t[r][c + 2] = f2bf(v.z); t[r][c + 3] = f2bf(v.w);
  }
  __syncthreads();
  u16* dst = wbt + ((size_t)e << 20);
#pragma unroll
  for (int p = 0; p < 4; ++p) {
    int orow = r_ + p * 16;
    ushort4 u;
    u.x = t[c + 0][orow]; u.y = t[c + 1][orow];
    u.z = t[c + 2][orow]; u.w = t[c + 3][orow];
    *reinterpret_cast<ushort4*>(dst + (size_t)(o0 + orow) * 1024 + i0 + c) = u;
  }
}

// ------- kernel 3: K-outer / expert-inner, swapped-operand Horner GEMM ----
// Block: batch 256 x o 128. 8 waves 2(o) x 4(batch): per wave o64 x batch64.
// mfma(Wfrag, xfrag): D col = batch (lane&15), D row = o. x-frags (B-op) in
// regs across all 8 expert phases of a K-tile; Horner rescale per phase with
// per-lane SCALAR ratios (all 32 in regs, loaded once).  w' = max(w, 3e-3).
// Per phase: stage W(g+3) (2 GLDS, 4 bufs); [g0,g1: stage x(kk+1) 2 GLDS];
// read wnext(8); [g>=4: read xnext(2)]; VM(c); LGKM(r); SB0; barrier;
// setprio; 32 MFMA; setprio; rescale.  One barrier/phase.
// Ledger: VM(c_g)=issues(this phase) -> all staged <= g-1 drained; buffer
// staged at g-2 is drained at g-1's VM, published g-1's barrier, read at g.
// LGKM(r_g)=reads(this phase) -> all older reads drained (in-order DS).
// LDS (u16 elems): x dbuf @0,@16384 (32KB ea); W bufs @32768+j*8192 (16KB,
// j=0..3). Total 65536 elems = 128KB.
__global__ __launch_bounds__(512, 2)
void zgemm(const u16* __restrict__ xb, const u16* __restrict__ wbt,
           const float* __restrict__ wts, const float* __restrict__ bias,
           float* __restrict__ y) {
  __shared__ u16 sm[65536];
  const char* smb = (const char*)sm;

  const int tid = threadIdx.x;
  const int l   = tid & 63;
  const int w   = tid >> 6;
  const int wo  = w >> 2;                    // 0..1  (o half)
  const int wb  = w & 3;                     // 0..3  (batch quarter)
  const int n0  = (blockIdx.x & 7) * 128;    // o panel: W 2MB L2-resident/XCD
  const int b0  = (blockIdx.x >> 3) * 256;   // batch panel

  const int l15   = l & 15;
  const int kpart = (l >> 4) << 4;

  // ---- per-lane ratio table (regs): rr[e][bb] = w'_e/w'_{(e+1)&7}
  float rr[8][4], w0t[4];
#pragma unroll
  for (int bb = 0; bb < 4; ++bb) {
    const int row = b0 + wb * 64 + bb * 16 + l15;
    float4 wlo_ = *reinterpret_cast<const float4*>(wts + (size_t)row * 8);
    float4 whi_ = *reinterpret_cast<const float4*>(wts + (size_t)row * 8 + 4);
    float wd[8] = {wlo_.x, wlo_.y, wlo_.z, wlo_.w, whi_.x, whi_.y, whi_.z, whi_.w};
#pragma unroll
    for (int e = 0; e < 8; ++e) wd[e] = fmaxf(wd[e], 3e-3f);
#pragma unroll
    for (int e = 0; e < 8; ++e) rr[e][bb] = wd[e] / wd[(e + 1) & 7];
    w0t[bb] = wd[0];
  }

  // ---- staging geometry (pre-swizzled global source, linear GLDS dest)
  const int rbl   = (w << 3) + (l >> 3);              // 0..63
  const int chunk = ((l & 7) ^ (l >> 3)) << 3;
  const u16* pXg = xb  + (size_t)(b0 + rbl) * 1024 + chunk;
  const u16* pWg = wbt + (size_t)(n0 + rbl) * 1024 + chunk;

  // ---- fragment read byte-offsets
  int xoff[4], woff[4];
#pragma unroll
  for (int bb = 0; bb < 4; ++bb) {
    const int r = wb * 64 + bb * 16 + l15;            // 0..255
    xoff[bb] = r * 128 + (kpart ^ ((r & 7) << 4));
  }
#pragma unroll
  for (int ob = 0; ob < 4; ++ob) {
    const int r = wo * 64 + ob * 16 + l15;            // 0..127
    woff[ob] = r * 128 + (kpart ^ ((r & 7) << 4));
  }

  f32x4 acc[4][4];
#pragma unroll
  for (int ob = 0; ob < 4; ++ob)
#pragma unroll
    for (int bb = 0; bb < 4; ++bb) acc[ob][bb] = (f32x4){0.f, 0.f, 0.f, 0.f};

  bf16x8 xA[8], xB[8], wA[8], wB[8];

  // ---- prologue: x(kk=0)->xpar0 (4 GLDS); W0,W1,W2 -> wbuf0,1,2 (6 GLDS)
#pragma unroll
  for (int q = 0; q < 4; ++q)
    GLDS16(pXg + (size_t)q * 65536, sm + q * 4096 + (w << 9));
#pragma unroll
  for (int g = 0; g < 3; ++g) {
    GLDS16(pWg + (size_t)g * 1048576,          sm + 32768 + g * 8192 + (w << 9));
    GLDS16(pWg + (size_t)g * 1048576 + 65536,  sm + 32768 + g * 8192 + 4096 + (w << 9));
  }
  asm volatile("s_waitcnt vmcnt(0)" ::: "memory");
  asm volatile("s_waitcnt lgkmcnt(0)" ::: "memory");
  __builtin_amdgcn_s_barrier();

  // preload xcur (xA from xpar0) and wcur (wA from wbuf0)
#pragma unroll
  for (int bb = 0; bb < 4; ++bb) {
    xA[2 * bb]     = *(const bf16x8*)(smb + xoff[bb]);
    xA[2 * bb + 1] = *(const bf16x8*)(smb + (xoff[bb] ^ 64));
  }
#pragma unroll
  for (int ob = 0; ob < 4; ++ob) {
    wA[2 * ob]     = *(const bf16x8*)(smb + 65536 + woff[ob]);
    wA[2 * ob + 1] = *(const bf16x8*)(smb + 65536 + (woff[ob] ^ 64));
  }

// XSP: stage parity dest (elems) for x(kk+1); XNB: next-parity read base (bytes)
#define PHASE(G, KK, XC, XN, WC, WN, XSP, XNB, VMC, LGC)                   \
  {                                                                        \
    { /* stage W((G+3)&7) of k-tile (KK + ((G+3)>>3)) & 15, dist-3 */      \
      const u16* s = pWg + (size_t)(((G) + 3) & 7) * 1048576               \
                   + (size_t)(((KK) + (((G) + 3) >> 3)) & 15) * 64;        \
      GLDS16(s,         sm + 32768 + (((G) + 3) & 3) * 8192 + (w << 9));   \
      GLDS16(s + 65536, sm + 32768 + (((G) + 3) & 3) * 8192 + 4096 + (w << 9)); \
    }                                                                      \
    if ((G) == 0) {                                                        \
      GLDS16(pXg + (size_t)(((KK) + 1) & 15) * 64,                         \
             sm + (XSP) + (w << 9));                                       \
      GLDS16(pXg + (size_t)(((KK) + 1) & 15) * 64 + 65536,                 \
             sm + (XSP) + 4096 + (w << 9));                                \
    }                                                                      \
    if ((G) == 1) {                                                        \
      GLDS16(pXg + (size_t)(((KK) + 1) & 15) * 64 + 131072,                \
             sm + (XSP) + 8192 + (w << 9));                                \
      GLDS16(pXg + (size_t)(((KK) + 1) & 15) * 64 + 196608,                \
             sm + (XSP) + 12288 + (w << 9));                               \
    }                                                                      \
    _Pragma("unroll")   /* wnext from wbuf[(G+1)&3] (8 reads) */           \
    for (int ob = 0; ob < 4; ++ob) {                                       \
      WN[2 * ob]     = *(const bf16x8*)(smb + 65536 + (((G) + 1) & 3) * 16384 + woff[ob]); \
      WN[2 * ob + 1] = *(const bf16x8*)(smb + 65536 + (((G) + 1) & 3) * 16384 + (woff[ob] ^ 64)); \
    }                                                                      \
    if ((G) >= 4) {     /* xnext frags 2(G-4), 2(G-4)+1 */                 \
      XN[2 * ((G) & 3)]     = *(const bf16x8*)(smb + (XNB) + xoff[(G) & 3]); \
      XN[2 * ((G) & 3) + 1] = *(const bf16x8*)(smb + (XNB) + (xoff[(G) & 3] ^ 64)); \
    }                                                                      \
    asm volatile("s_waitcnt vmcnt(" #VMC ")" ::: "memory");                \
    asm volatile("s_waitcnt lgkmcnt(" #LGC ")" ::: "memory");              \
    SB0;                                                                   \
    __builtin_amdgcn_s_barrier();                                          \
    SB0;                                                                   \
    __builtin_amdgcn_s_setprio(1);                                         \
    _Pragma("unroll")                                                      \
    for (int ob = 0; ob < 4; ++ob)                                         \
      _Pragma("unroll")                                                    \
      for (int bb = 0; bb < 4; ++bb) {                                     \
        acc[ob][bb] = MFMA_BF16(WC[2 * ob], XC[2 * bb], acc[ob][bb], 0, 0, 0); \
        acc[ob][bb] = MFMA_BF16(WC[2 * ob + 1], XC[2 * bb + 1], acc[ob][bb], 0, 0, 0); \
      }                                                                    \
    __builtin_amdgcn_s_setprio(0);                                         \
    _Pragma("unroll")   /* Horner rescale: per-lane scalar per bb */       \
    for (int ob = 0; ob < 4; ++ob)                                         \
      _Pragma("unroll")                                                    \
      for (int bb = 0; bb < 4; ++bb) acc[ob][bb] *= rr[(G)][bb];           \
  }

#pragma unroll 1
  for (int kk = 0; kk < 16; kk += 2) {
    // even body: xcur = xA (par0), stage/next = par1 (elems 16384, bytes 32768)
    PHASE(0, kk, xA, xB, wA, wB, 16384, 32768, 4, 8)
    PHASE(1, kk, xA, xB, wB, wA, 16384, 32768, 4, 8)
    PHASE(2, kk, xA, xB, wA, wB, 16384, 32768, 2, 8)
    PHASE(3, kk, xA, xB, wB, wA, 16384, 32768, 2, 8)
    PHASE(4, kk, xA, xB, wA, wB, 16384, 32768, 2, 10)
    PHASE(5, kk, xA, xB, wB, wA, 16384, 32768, 2, 10)
    PHASE(6, kk, xA, xB, wA, wB, 16384, 32768, 2, 10)
    PHASE(7, kk, xA, xB, wB, wA, 16384, 32768, 2, 10)
    // odd body: xcur = xB (par1), stage/next = par0 (elems 0, bytes 0)
    PHASE(0, kk + 1, xB, xA, wA, wB, 0, 0, 4, 8)
    PHASE(1, kk + 1, xB, xA, wB, wA, 0, 0, 4, 8)
    PHASE(2, kk + 1, xB, xA, wA, wB, 0, 0, 2, 8)
    PHASE(3, kk + 1, xB, xA, wB, wA, 0, 0, 2, 8)
    PHASE(4, kk + 1, xB, xA, wA, wB, 0, 0, 2, 10)
    PHASE(5, kk + 1, xB, xA, wB, wA, 0, 0, 2, 10)
    PHASE(6, kk + 1, xB, xA, wA, wB, 0, 0, 2, 10)
    PHASE(7, kk + 1, xB, xA, wB, wA, 0, 0, 2, 10)
  }
  asm volatile("s_waitcnt vmcnt(0)" ::: "memory");
  asm volatile("s_waitcnt lgkmcnt(0)" ::: "memory");

  // ---- epilogue: y = w'_0 * acc + sum_e w_e * bias_e   (acc is in w'_0 units)
  float wt[8][4];
#pragma unroll
  for (int bb = 0; bb < 4; ++bb) {
    const int row = b0 + wb * 64 + bb * 16 + l15;
    float4 wlo_ = *reinterpret_cast<const float4*>(wts + (size_t)row * 8);
    float4 whi_ = *reinterpret_cast<const float4*>(wts + (size_t)row * 8 + 4);
    wt[0][bb] = wlo_.x; wt[1][bb] = wlo_.y; wt[2][bb] = wlo_.z; wt[3][bb] = wlo_.w;
    wt[4][bb] = whi_.x; wt[5][bb] = whi_.y; wt[6][bb] = whi_.z; wt[7][bb] = whi_.w;
  }
#pragma unroll
  for (int ob = 0; ob < 4; ++ob) {
#pragma unroll
    for (int j = 0; j < 4; ++j) {
      const int o = n0 + wo * 64 + ob * 16 + ((l >> 4) << 2) + j;
      float be[8];
#pragma unroll
      for (int e = 0; e < 8; ++e) be[e] = bias[(size_t)e * OUT_DIM + o];
#pragma unroll
      for (int bb = 0; bb < 4; ++bb) {
        const int row = b0 + wb * 64 + bb * 16 + l15;
        float v = acc[ob][bb][j] * w0t[bb];
#pragma unroll
        for (int e = 0; e < 8; ++e) v += wt[e][bb] * be[e];
        y[(size_t)row * OUT_DIM + o] = v;
      }
    }
  }
}

extern "C" void kernel_launch(void* const* d_in, const int* in_sizes, int n_in,
                              void* d_out, int out_size, void* d_ws, size_t ws_size,
                              hipStream_t stream) {
  const float* x    = (const float*)d_in[0];
  const float* wts  = (const float*)d_in[1];
  const float* W    = (const float*)d_in[2];
  const float* bias = (const float*)d_in[3];
  float* y = (float*)d_out;

  const size_t xb_elems = (size_t)BATCH * IN_DIM;                 // 32 MB bf16
  const size_t wb_elems = (size_t)EXPERTS * IN_DIM * OUT_DIM;     // 16 MB bf16
  if (ws_size < (xb_elems + wb_elems) * sizeof(u16)) return;      // loud failure
  u16* xb  = (u16*)d_ws;
  u16* wbt = xb + xb_elems;

  cvt_x<<<(BATCH * IN_DIM) / (4 * 256), 256, 0, stream>>>(x, xb);
  cvt_w<<<dim3(IN_DIM / 64, OUT_DIM / 64, EXPERTS), 256, 0, stream>>>(W, wbt);
  zgemm<<<dim3((BATCH / 256) * (OUT_DIM / 128)), 512, 0, stream>>>(xb, wbt, wts, bias, y);
}

// Round 13
// 279.997 us; speedup vs baseline: 2.3230x; 2.3230x over previous
//
#include <hip/hip_runtime.h>
#include <hip/hip_bf16.h>
#include <stdint.h>

#define BATCH   16384
#define EXPERTS 8
#define IN_DIM  1024
#define OUT_DIM 1024

typedef unsigned short u16;
typedef short  bf16x8 __attribute__((ext_vector_type(8)));
typedef float  f32x4  __attribute__((ext_vector_type(4)));

__device__ __forceinline__ u16 f2bf(float f) {
  uint32_t u = __float_as_uint(f);
  u += 0x7fffu + ((u >> 16) & 1u);   // RNE
  return (u16)(u >> 16);
}

#define GLDS16(g, l)                                                      \
  __builtin_amdgcn_global_load_lds(                                       \
      (const __attribute__((address_space(1))) void*)(g),                 \
      (__attribute__((address_space(3))) void*)(l), 16, 0, 0)

#define MFMA_BF16 __builtin_amdgcn_mfma_f32_16x16x32_bf16
#define SB0 __builtin_amdgcn_sched_barrier(0)
#define LGKM(N) asm volatile("s_waitcnt lgkmcnt(" #N ")" ::: "memory")
#define VMC(N)  asm volatile("s_waitcnt vmcnt(" #N ")" ::: "memory")

// ---------------- kernel 1: x fp32 -> bf16 ----------------
__global__ void cvt_x(const float* __restrict__ x, u16* __restrict__ xb) {
  size_t i = ((size_t)blockIdx.x * 256 + threadIdx.x) * 4;
  float4 v = *reinterpret_cast<const float4*>(x + i);
  ushort4 o;
  o.x = f2bf(v.x); o.y = f2bf(v.y); o.z = f2bf(v.z); o.w = f2bf(v.w);
  *reinterpret_cast<ushort4*>(xb + i) = o;
}

// -- kernel 2: W[e][i][o] f32 -> fragment-stream bf16 -----------------------
// wtp elem idx = (e*16+kt)*65536 + ob*1024 + kf*512 + lane*8 + j
// where o = ob*16 + (lane&15), i = kt*64 + kf*32 + (lane>>4)*8 + j.
// A wave's B-frag load is then 64 lanes x 16B contiguous (1KB, coalesced).
__global__ void cvt_wp(const float* __restrict__ W, u16* __restrict__ wtp) {
  __shared__ u16 tl[64][260];
  const int kt = blockIdx.x, og = blockIdx.y, e = blockIdx.z;
  const int t = threadIdx.x;
  const float* src = W + ((size_t)e << 20) + (size_t)kt * 64 * 1024 + og * 256;
#pragma unroll
  for (int p = 0; p < 16; ++p) {
    int flat = p * 256 + t;            // float4 index within 64x256 tile
    int i  = flat >> 6;
    int o4 = (flat & 63) * 4;
    float4 v = *reinterpret_cast<const float4*>(src + (size_t)i * 1024 + o4);
    tl[i][o4 + 0] = f2bf(v.x); tl[i][o4 + 1] = f2bf(v.y);
    tl[i][o4 + 2] = f2bf(v.z); tl[i][o4 + 3] = f2bf(v.w);
  }
  __syncthreads();
  u16* dst = wtp + (size_t)(e * 16 + kt) * 65536 + (size_t)og * 16 * 1024;
#pragma unroll
  for (int s = 0; s < 8; ++s) {
    int c   = s * 256 + t;             // chunk 0..2047
    int obl = c >> 7;                  // 0..15 (local ob)
    int kf  = (c >> 6) & 1;
    int ln  = c & 63;
    int ol  = obl * 16 + (ln & 15);
    int ib  = kf * 32 + ((ln >> 4) << 3);
    u16 buf[8];
#pragma unroll
    for (int j = 0; j < 8; ++j) buf[j] = tl[ib + j][ol];
    u16* d = dst + (size_t)obl * 1024 + kf * 512 + ln * 8;
    *reinterpret_cast<ushort4*>(d)     = *(ushort4*)&buf[0];
    *reinterpret_cast<ushort4*>(d + 4) = *(ushort4*)&buf[4];
  }
}

// ---- kernel 3: Horner GEMM; A via LDS (r10 schedule), B direct from L2 ----
// BM=BN=256 BK=64, 512 thr = 8 waves (2M x 4N), wave 128x64, acc 128 VGPR.
// B-frags stream global->reg (fragment-packed wtp), double-buffered one tile
// ahead (bE/bO).  LDS carries A only: reads 128KB + writes 32KB per tile
// (was 192KB+64KB) -> LDS-read roofline drops ~1.45x.
// Ledger/tile: top {4 GLDS A(t+1) | SB0 | 8 B(t+1) loads | SB0 | F1(4)};
// LGKM(4)->F0, issue F2, P0; LGKM(4)->F1, issue F3, P1; VMC(8) drains the
// 4 GLDS exactly (8 B-loads younger, stay in flight); MID barrier publishes
// A(t+1); LGKM(4)->F2, issue F0'(parity q), P2; LGKM(4)->F3, P3; boundary
// rescale (LGKM(0) flush, 7x); END barrier (recycle gate).
// LDS (u16): A dbuf @0,@16384 (32KB ea); rl f32[8][256] @32768 (8KB) = 72KB.
__global__ __launch_bounds__(512, 1)
void zgemm(const u16* __restrict__ xb, const u16* __restrict__ wtp,
           const float* __restrict__ wts, const float* __restrict__ bias,
           float* __restrict__ y) {
  __shared__ u16 sm[36864];
  const char* smb = (const char*)sm;
  float* rl = (float*)(sm + 32768);          // byte 65536

  const int tid = threadIdx.x;
  const int l   = tid & 63;
  const int w   = tid >> 6;
  const int wm  = w >> 2;                    // 0..1
  const int wn  = w & 3;                     // 0..3
  const int x8  = blockIdx.x & 7;
  const int jj  = blockIdx.x >> 3;
  const int n0  = (x8 >> 1) * 256;           // XCD-pair owns one W-panel (4MB)
  const int b0  = (((x8 & 1) << 5) + jj) << 8;

  // ---- ratio table rl[e][256]: e<7 -> w'_e/w'_{e+1}; rl[7] = w'_7
#pragma unroll
  for (int i = 0; i < 4; ++i) {
    const int flat = tid + i * 512;
    const int e = flat & 7, r = flat >> 3;
    const float* wr = wts + (size_t)(b0 + r) * EXPERTS;
    float we = fmaxf(wr[e], 1e-20f);
    float rr = (e < 7) ? we / fmaxf(wr[e + 1], 1e-20f) : we;
    rl[e * 256 + r] = rr;
  }

  // ---- A staging geometry (pre-swizzled global source, linear GLDS dest)
  const int rbl   = (w << 3) + (l >> 3);
  const int chunk = ((l & 7) ^ (l >> 3)) << 3;
  const u16* pAg = xb + (size_t)(b0 + rbl) * IN_DIM + chunk;

  // ---- A fragment read keys (r10)
  const int l15  = l & 15;
  const int kb0  = (((l >> 4) << 4)) ^ ((l & 7) << 4);   // kf0; kf1 = ^64
  const int arow = (wm * 128 + l15) * 128;               // + m*2048
  const int wlo  = (wm << 9) + ((l >> 4) << 4);          // rl byte off + m*64

  // ---- B fragment stream base: lane-chunk + this block/wave's ob base
  const int obBase = (n0 >> 4) + wn * 4;                 // o-block-16 index
  const u16* pBf = wtp + (size_t)obBase * 1024 + (size_t)l * 8;

  f32x4 acc[8][4];
#pragma unroll
  for (int m = 0; m < 8; ++m)
#pragma unroll
    for (int n = 0; n < 4; ++n) acc[m][n] = (f32x4){0.f, 0.f, 0.f, 0.f};

#define STG_A(q, dstE, kv)                                                 \
  GLDS16(pAg + (size_t)((q) * 64) * 1024 + (size_t)(kv) * 64,              \
         sm + (dstE) + (q) * 4096 + (w << 9))

#define MM(AV, BV, MB)                                                     \
  __builtin_amdgcn_s_setprio(1);                                           \
  _Pragma("unroll")                                                        \
  for (int m = 0; m < 4; ++m)                                              \
    _Pragma("unroll")                                                      \
    for (int n = 0; n < 4; ++n)                                            \
      acc[(MB) + m][n] = MFMA_BF16(AV[m], BV[n], acc[(MB) + m][n], 0, 0, 0); \
  __builtin_amdgcn_s_setprio(0);

  bf16x8 a0[4];                      // loop-carried F0
  bf16x8 bEk0[4], bEk1[4], bOk0[4], bOk1[4];   // B double-buffer

  // ---- prologue: A(0) -> parity 0; B(0) -> bE; drain; publish; F0 reads
  STG_A(0, 0, 0); STG_A(1, 0, 0); STG_A(2, 0, 0); STG_A(3, 0, 0);
#pragma unroll
  for (int nf = 0; nf < 4; ++nf) {
    bEk0[nf] = *(const bf16x8*)(pBf + (size_t)nf * 1024);
    bEk1[nf] = *(const bf16x8*)(pBf + (size_t)nf * 1024 + 512);
  }
  VMC(0);
  LGKM(0);                                   // rl ds_writes drained
  __builtin_amdgcn_s_barrier();
#pragma unroll
  for (int m = 0; m < 4; ++m)
    a0[m] = *(const bf16x8*)(smb + arow + m * 2048 + kb0);

// BODY: TT = tile index expr; BCk0/BCk1 current B; BNk0/BNk1 next B;
// ARB = parity read base (bytes), AWE = parity write base (elems).
#define BODY(TT, BCk0, BCk1, BNk0, BNk1, ARB, AWE)                         \
  {                                                                        \
    const int tn = ((TT) + 1) & 127;                                       \
    const int e1 = tn >> 4, k1 = tn & 15;                                  \
    bf16x8 a1[4], a2[4], a3[4];                                            \
    /* top: 4 GLDS A(t+1) | SB0 | 8 B(t+1) loads | SB0 | F1 */             \
    STG_A(0, AWE, k1); STG_A(1, AWE, k1); STG_A(2, AWE, k1); STG_A(3, AWE, k1); \
    SB0;                                                                   \
    {                                                                      \
      const u16* pb = pBf + (size_t)(e1 * 16 + k1) * 65536;                \
      _Pragma("unroll")                                                    \
      for (int nf = 0; nf < 4; ++nf) {                                     \
        BNk0[nf] = *(const bf16x8*)(pb + (size_t)nf * 1024);               \
        BNk1[nf] = *(const bf16x8*)(pb + (size_t)nf * 1024 + 512);         \
      }                                                                    \
    }                                                                      \
    SB0;                                                                   \
    _Pragma("unroll")                                                      \
    for (int m = 0; m < 4; ++m)                                            \
      a1[m] = *(const bf16x8*)(smb + (ARB) + arow + (m + 4) * 2048 + kb0); \
    LGKM(4); SB0;                          /* F0 done */                   \
    _Pragma("unroll")                                                      \
    for (int m = 0; m < 4; ++m)                                            \
      a2[m] = *(const bf16x8*)(smb + (ARB) + arow + m * 2048 + (kb0 ^ 64)); \
    MM(a0, BCk0, 0)                        /* P0 */                        \
    LGKM(4); SB0;                          /* F1 done */                   \
    _Pragma("unroll")                                                      \
    for (int m = 0; m < 4; ++m)                                            \
      a3[m] = *(const bf16x8*)(smb + (ARB) + arow + (m + 4) * 2048 + (kb0 ^ 64)); \
    MM(a1, BCk0, 4)                        /* P1 */                        \
    VMC(8);                                /* 4 GLDS done; 8 B in flight */ \
    __builtin_amdgcn_s_barrier();          /* MID: publish A(t+1) */       \
    LGKM(4); SB0;                          /* F2 done */                   \
    _Pragma("unroll")                                                      \
    for (int m = 0; m < 4; ++m)            /* F0' from parity q */         \
      a0[m] = *(const bf16x8*)(smb + ((ARB) ^ 32768) + arow + m * 2048 + kb0); \
    MM(a2, BCk1, 0)                        /* P2 */                        \
    LGKM(4); SB0;                          /* F3 done (F0' in flight) */   \
    MM(a3, BCk1, 4)                        /* P3 */                        \
    if (((TT) & 15) == 15 && (TT) != 127) {                                \
      const int e = (TT) >> 4;                                             \
      f32x4 rv[8];                                                         \
      _Pragma("unroll")                                                    \
      for (int m = 0; m < 8; ++m)                                          \
        rv[m] = *(const f32x4*)(smb + 65536 + e * 1024 + wlo + m * 64);    \
      LGKM(0); SB0;                                                        \
      _Pragma("unroll")                                                    \
      for (int m = 0; m < 8; ++m)                                          \
        _Pragma("unroll")                                                  \
        for (int n = 0; n < 4; ++n) acc[m][n] *= rv[m];                    \
    }                                                                      \
    __builtin_amdgcn_s_barrier();          /* END: recycle gate */         \
  }

#pragma unroll 1
  for (int t = 0; t < 128; t += 2) {
    BODY(t,     bEk0, bEk1, bOk0, bOk1, 0,     16384)
    BODY(t + 1, bOk0, bOk1, bEk0, bEk1, 32768, 0)
  }
  VMC(0); LGKM(0);

  // ---- epilogue: y = w'_7 * acc + sum_e w_e * bias_e
  float bv[4][8];
#pragma unroll
  for (int n = 0; n < 4; ++n) {
    const int c = n0 + wn * 64 + n * 16 + l15;
#pragma unroll
    for (int ee = 0; ee < 8; ++ee) bv[n][ee] = bias[ee * OUT_DIM + c];
  }
#pragma unroll
  for (int m = 0; m < 8; ++m) {
    const f32x4 rv7 = *(const f32x4*)(smb + 65536 + 7 * 1024 + wlo + m * 64);
    const int r0 = b0 + wm * 128 + m * 16 + ((l >> 4) << 2);
#pragma unroll
    for (int j = 0; j < 4; ++j) {
      const float* wr = wts + (size_t)(r0 + j) * EXPERTS;
      float w8[8];
#pragma unroll
      for (int ee = 0; ee < 8; ++ee) w8[ee] = wr[ee];
#pragma unroll
      for (int n = 0; n < 4; ++n) {
        const int c = n0 + wn * 64 + n * 16 + l15;
        float v = acc[m][n][j] * rv7[j];
#pragma unroll
        for (int ee = 0; ee < 8; ++ee) v += w8[ee] * bv[n][ee];
        y[(size_t)(r0 + j) * OUT_DIM + c] = v;
      }
    }
  }
}

extern "C" void kernel_launch(void* const* d_in, const int* in_sizes, int n_in,
                              void* d_out, int out_size, void* d_ws, size_t ws_size,
                              hipStream_t stream) {
  const float* x    = (const float*)d_in[0];
  const float* wts  = (const float*)d_in[1];
  const float* W    = (const float*)d_in[2];
  const float* bias = (const float*)d_in[3];
  float* y = (float*)d_out;

  const size_t xb_elems = (size_t)BATCH * IN_DIM;                 // 32 MB bf16
  const size_t wp_elems = (size_t)EXPERTS * IN_DIM * OUT_DIM;     // 16 MB bf16
  if (ws_size < (xb_elems + wp_elems) * sizeof(u16)) return;      // loud failure
  u16* xb  = (u16*)d_ws;
  u16* wtp = xb + xb_elems;

  cvt_x<<<(BATCH * IN_DIM) / (4 * 256), 256, 0, stream>>>(x, xb);
  cvt_wp<<<dim3(16, 4, 8), 256, 0, stream>>>(W, wtp);
  zgemm<<<dim3(256), 512, 0, stream>>>(xb, wtp, wts, bias, y);
}

// Round 14
// 262.096 us; speedup vs baseline: 2.4816x; 1.0683x over previous
//
#include <hip/hip_runtime.h>
#include <hip/hip_bf16.h>
#include <stdint.h>

#define BATCH   16384
#define EXPERTS 8
#define IN_DIM  1024
#define OUT_DIM 1024

typedef unsigned short u16;
typedef short  bf16x8 __attribute__((ext_vector_type(8)));
typedef float  f32x4  __attribute__((ext_vector_type(4)));

__device__ __forceinline__ u16 f2bf(float f) {
  uint32_t u = __float_as_uint(f);
  u += 0x7fffu + ((u >> 16) & 1u);   // RNE
  return (u16)(u >> 16);
}

#define GLDS16(g, l)                                                      \
  __builtin_amdgcn_global_load_lds(                                       \
      (const __attribute__((address_space(1))) void*)(g),                 \
      (__attribute__((address_space(3))) void*)(l), 16, 0, 0)

#define MFMA_BF16 __builtin_amdgcn_mfma_f32_16x16x32_bf16
#define SB0 __builtin_amdgcn_sched_barrier(0)
#define LGKM(N) asm volatile("s_waitcnt lgkmcnt(" #N ")" ::: "memory")
#define VMC(N)  asm volatile("s_waitcnt vmcnt(" #N ")" ::: "memory")

// ---------------- kernel 1: x fp32 -> bf16 ----------------
__global__ void cvt_x(const float* __restrict__ x, u16* __restrict__ xb) {
  size_t i = ((size_t)blockIdx.x * 256 + threadIdx.x) * 4;
  float4 v = *reinterpret_cast<const float4*>(x + i);
  ushort4 o;
  o.x = f2bf(v.x); o.y = f2bf(v.y); o.z = f2bf(v.z); o.w = f2bf(v.w);
  *reinterpret_cast<ushort4*>(xb + i) = o;
}

// ------- kernel 2: W[e][i][o] fp32 -> Wbt[e][o][i] bf16 (transpose) -------
__global__ void cvt_w(const float* __restrict__ W, u16* __restrict__ wbt) {
  __shared__ u16 t[64][72];
  const int e  = blockIdx.z;
  const int i0 = blockIdx.x * 64;
  const int o0 = blockIdx.y * 64;
  const int tid = threadIdx.x;
  const int c  = (tid & 15) * 4;
  const int r_ = tid >> 4;
  const float* src = W + ((size_t)e << 20);
#pragma unroll
  for (int p = 0; p < 4; ++p) {
    int r = r_ + p * 16;
    float4 v = *reinterpret_cast<const float4*>(src + (size_t)(i0 + r) * 1024 + o0 + c);
    t[r][c + 0] = f2bf(v.x); t[r][c + 1] = f2bf(v.y);
    t[r][c + 2] = f2bf(v.z); t[r][c + 3] = f2bf(v.w);
  }
  __syncthreads();
  u16* dst = wbt + ((size_t)e << 20);
#pragma unroll
  for (int p = 0; p < 4; ++p) {
    int orow = r_ + p * 16;
    ushort4 u;
    u.x = t[c + 0][orow]; u.y = t[c + 1][orow];
    u.z = t[c + 2][orow]; u.w = t[c + 3][orow];
    *reinterpret_cast<ushort4*>(dst + (size_t)(o0 + orow) * 1024 + i0 + c) = u;
  }
}

// ------- kernel 3: Horner GEMM, m201-style per-phase interleave -----------
// BM=BN=256 BK=64, 512 thr = 8 waves (2M x 4N), wave 128x64, acc 128 VGPR.
// 4 phases/tile, each: {reads for THIS phase (before barrier, latency hides
// under barrier wait); 2 stage GLDS (consumption order); [vmcnt(2) at P0,P3];
// barrier; lgkm(0); SB0; setprio(1); 16 MFMA; setprio(0); barrier}.
// Stage order: P0 B01(t+1), P1 B23, P2 A02, P3 A13.
// Ledger/wave: P3 vmcnt(2) [outstanding 8 -> drains B01+B23+A02, published
// by P3's pre-MM barrier, read at (t+1).P0-top]; P0 vmcnt(2) [outstanding 4
// -> drains A13(t), published for P1-top].  Never vmcnt(0) in loop.
// Horner: acc *= w'_e/w'_{e+1} at expert boundary (7x, rl in LDS).
// LDS (u16 elems): A dbuf @0,@16384; B dbuf @32768,@49152; rl @65536 (4096).
__global__ __launch_bounds__(512, 2)
void zgemm(const u16* __restrict__ xb, const u16* __restrict__ wbt,
           const float* __restrict__ wts, const float* __restrict__ bias,
           float* __restrict__ y) {
  __shared__ u16 sm[69632];
  char* smb = (char*)sm;
  float* rl = (float*)(sm + 65536);          // byte 131072

  const int tid = threadIdx.x;
  const int l   = tid & 63;
  const int w   = tid >> 6;
  const int wm  = w >> 2;                    // 0..1
  const int wn  = w & 3;                     // 0..3
  const int x8  = blockIdx.x & 7;
  const int jj  = blockIdx.x >> 3;
  const int n0  = (x8 >> 1) * 256;           // XCD-pair owns one B-panel (4MB)
  const int b0  = (((x8 & 1) << 5) + jj) << 8;

  // ---- ratio table rl[e][256]: e<7 -> w'_e/w'_{e+1}; rl[7] = w'_7
#pragma unroll
  for (int i = 0; i < 4; ++i) {
    const int flat = tid + i * 512;
    const int e = flat & 7, r = flat >> 3;
    const float* wr = wts + (size_t)(b0 + r) * EXPERTS;
    float we = fmaxf(wr[e], 1e-20f);
    float rr = (e < 7) ? we / fmaxf(wr[e + 1], 1e-20f) : we;
    rl[e * 256 + r] = rr;
  }

  // ---- staging geometry (pre-swizzled global source, linear GLDS dest)
  const int rbl   = (w << 3) + (l >> 3);
  const int chunk = ((l & 7) ^ (l >> 3)) << 3;
  const u16* pAg = xb  + (size_t)(b0 + rbl) * IN_DIM + chunk;
  const u16* pBg = wbt + (size_t)(n0 + rbl) * 1024 + chunk;

  // ---- fragment read keys
  const int l15  = l & 15;
  const int kb0  = (((l >> 4) << 4)) ^ ((l & 7) << 4);   // kf0; kf1 = ^64
  const int arow = (wm * 128 + l15) * 128;               // + m*2048
  const int brow = (wn * 64 + l15) * 128;                // + n*2048
  const int wlo  = (wm << 9) + ((l >> 4) << 4);          // rl byte off + m*64

  f32x4 acc[8][4];
#pragma unroll
  for (int m = 0; m < 8; ++m)
#pragma unroll
    for (int n = 0; n < 4; ++n) acc[m][n] = (f32x4){0.f, 0.f, 0.f, 0.f};

#define STG_A(q, dstE, kv)                                                 \
  GLDS16(pAg + (size_t)((q) * 64) * 1024 + (size_t)(kv) * 64,              \
         sm + (dstE) + (q) * 4096 + (w << 9))
#define STG_B(q, dstE, off)                                                \
  GLDS16(pBg + (off) + (size_t)((q) * 64) * 1024,                          \
         sm + (dstE) + (q) * 4096 + (w << 9))

#define MM(AV, BV, MB)                                                     \
  __builtin_amdgcn_s_setprio(1);                                           \
  _Pragma("unroll")                                                        \
  for (int m = 0; m < 4; ++m)                                              \
    _Pragma("unroll")                                                      \
    for (int n = 0; n < 4; ++n)                                            \
      acc[(MB) + m][n] = MFMA_BF16(AV[m], BV[n], acc[(MB) + m][n], 0, 0, 0); \
  __builtin_amdgcn_s_setprio(0);

  // ---- prologue: tile 0 -> parity-0 buffers; full drain; publish
  STG_A(0, 0, 0); STG_A(1, 0, 0); STG_A(2, 0, 0); STG_A(3, 0, 0);
  STG_B(0, 32768, 0); STG_B(1, 32768, 0); STG_B(2, 32768, 0); STG_B(3, 32768, 0);
  VMC(0);
  LGKM(0);                                   // rl ds_writes drained
  __builtin_amdgcn_s_barrier();

#pragma unroll 1
  for (int t = 0; t < 128; ++t) {
    const int tn  = (t + 1) & 127;                 // wrap at 127 (harmless)
    const int e1  = tn >> 4, k1 = tn & 15;
    const int ArB = (t & 1) << 15;                 // A read base (bytes)
    const int BrB = 65536 + ((t & 1) << 15);       // B read base (bytes)
    const int AwE = ((t + 1) & 1) << 14;           // A stage base (elems)
    const int BwE = 32768 + (((t + 1) & 1) << 14); // B stage base (elems)
    const size_t boffg = (size_t)e1 * 1048576 + (size_t)k1 * 64;

    bf16x8 a[4], b[4];

    // ---------------- P0 : kf0, m0-3 ----------------
#pragma unroll
    for (int m = 0; m < 4; ++m)
      a[m] = *(const bf16x8*)(smb + ArB + arow + m * 2048 + kb0);
#pragma unroll
    for (int n = 0; n < 4; ++n)
      b[n] = *(const bf16x8*)(smb + BrB + brow + n * 2048 + kb0);
    STG_B(0, BwE, boffg); STG_B(1, BwE, boffg);
    VMC(2);                                  // drains A13(t); leaves B01
    __builtin_amdgcn_s_barrier();            // publish A13(t) for P1-top
    LGKM(0); SB0;
    MM(a, b, 0)
    __builtin_amdgcn_s_barrier();

    // ---------------- P1 : kf0, m4-7 ----------------
    bf16x8 a1[4];
#pragma unroll
    for (int m = 0; m < 4; ++m)
      a1[m] = *(const bf16x8*)(smb + ArB + arow + (m + 4) * 2048 + kb0);
    STG_B(2, BwE, boffg); STG_B(3, BwE, boffg);
    __builtin_amdgcn_s_barrier();
    LGKM(0); SB0;
    MM(a1, b, 4)
    __builtin_amdgcn_s_barrier();

    // ---------------- P2 : kf1, m0-3 ----------------
    bf16x8 a2[4], b2[4];
#pragma unroll
    for (int m = 0; m < 4; ++m)
      a2[m] = *(const bf16x8*)(smb + ArB + arow + m * 2048 + (kb0 ^ 64));
#pragma unroll
    for (int n = 0; n < 4; ++n)
      b2[n] = *(const bf16x8*)(smb + BrB + brow + n * 2048 + (kb0 ^ 64));
    STG_A(0, AwE, k1); STG_A(2, AwE, k1);
    __builtin_amdgcn_s_barrier();
    LGKM(0); SB0;
    MM(a2, b2, 0)
    __builtin_amdgcn_s_barrier();

    // ---------------- P3 : kf1, m4-7 ----------------
    bf16x8 a3[4];
#pragma unroll
    for (int m = 0; m < 4; ++m)
      a3[m] = *(const bf16x8*)(smb + ArB + arow + (m + 4) * 2048 + (kb0 ^ 64));
    STG_A(1, AwE, k1); STG_A(3, AwE, k1);
    VMC(2);                  // drains B01+B23+A02(t+1); leaves A13(t+1)
    __builtin_amdgcn_s_barrier();            // publish for (t+1).P0-top
    LGKM(0); SB0;
    MM(a3, b2, 4)
    // ---- expert boundary: acc *= w'_e / w'_{e+1}  (7 times total)
    if ((t & 15) == 15 && t != 127) {
      const int e = t >> 4;
      f32x4 rv[8];
#pragma unroll
      for (int m = 0; m < 8; ++m)
        rv[m] = *(const f32x4*)(smb + 131072 + e * 1024 + wlo + m * 64);
      LGKM(0); SB0;
#pragma unroll
      for (int m = 0; m < 8; ++m)
#pragma unroll
        for (int n = 0; n < 4; ++n) acc[m][n] *= rv[m];
    }
    __builtin_amdgcn_s_barrier();
  }
  VMC(0); LGKM(0);

  // ---- epilogue: y = w'_7 * acc + sum_e w_e * bias_e
  float bv[4][8];
#pragma unroll
  for (int n = 0; n < 4; ++n) {
    const int c = n0 + wn * 64 + n * 16 + l15;
#pragma unroll
    for (int ee = 0; ee < 8; ++ee) bv[n][ee] = bias[ee * OUT_DIM + c];
  }
#pragma unroll
  for (int m = 0; m < 8; ++m) {
    const f32x4 rv7 = *(const f32x4*)(smb + 131072 + 7 * 1024 + wlo + m * 64);
    const int r0 = b0 + wm * 128 + m * 16 + ((l >> 4) << 2);
#pragma unroll
    for (int j = 0; j < 4; ++j) {
      const float* wr = wts + (size_t)(r0 + j) * EXPERTS;
      float w8[8];
#pragma unroll
      for (int ee = 0; ee < 8; ++ee) w8[ee] = wr[ee];
#pragma unroll
      for (int n = 0; n < 4; ++n) {
        const int c = n0 + wn * 64 + n * 16 + l15;
        float v = acc[m][n][j] * rv7[j];
#pragma unroll
        for (int ee = 0; ee < 8; ++ee) v += w8[ee] * bv[n][ee];
        y[(size_t)(r0 + j) * OUT_DIM + c] = v;
      }
    }
  }
}

extern "C" void kernel_launch(void* const* d_in, const int* in_sizes, int n_in,
                              void* d_out, int out_size, void* d_ws, size_t ws_size,
                              hipStream_t stream) {
  const float* x    = (const float*)d_in[0];
  const float* wts  = (const float*)d_in[1];
  const float* W    = (const float*)d_in[2];
  const float* bias = (const float*)d_in[3];
  float* y = (float*)d_out;

  const size_t xb_elems = (size_t)BATCH * IN_DIM;                 // 32 MB bf16
  const size_t wb_elems = (size_t)EXPERTS * IN_DIM * OUT_DIM;     // 16 MB bf16
  if (ws_size < (xb_elems + wb_elems) * sizeof(u16)) return;      // loud failure
  u16* xb  = (u16*)d_ws;
  u16* wbt = xb + xb_elems;

  cvt_x<<<(BATCH * IN_DIM) / (4 * 256), 256, 0, stream>>>(x, xb);
  cvt_w<<<dim3(IN_DIM / 64, OUT_DIM / 64, EXPERTS), 256, 0, stream>>>(W, wbt);
  zgemm<<<dim3(256), 512, 0, stream>>>(xb, wbt, wts, bias, y);
}

// Round 15
// 243.754 us; speedup vs baseline: 2.6684x; 1.0753x over previous
//
#include <hip/hip_runtime.h>
#include <hip/hip_bf16.h>
#include <stdint.h>

#define BATCH   16384
#define EXPERTS 8
#define IN_DIM  1024
#define OUT_DIM 1024

typedef unsigned short u16;
typedef short  bf16x8 __attribute__((ext_vector_type(8)));
typedef float  f32x4  __attribute__((ext_vector_type(4)));

__device__ __forceinline__ u16 f2bf(float f) {
  uint32_t u = __float_as_uint(f);
  u += 0x7fffu + ((u >> 16) & 1u);   // RNE
  return (u16)(u >> 16);
}

#define GLDS16(g, l)                                                      \
  __builtin_amdgcn_global_load_lds(                                       \
      (const __attribute__((address_space(1))) void*)(g),                 \
      (__attribute__((address_space(3))) void*)(l), 16, 0, 0)

#define MFMA_BF16 __builtin_amdgcn_mfma_f32_16x16x32_bf16
#define SB0 __builtin_amdgcn_sched_barrier(0)
#define LGKM(N) asm volatile("s_waitcnt lgkmcnt(" #N ")" ::: "memory")
#define VM0     asm volatile("s_waitcnt vmcnt(0)" ::: "memory")

// ---------------- kernel 1: x fp32 -> bf16 ----------------
__global__ void cvt_x(const float* __restrict__ x, u16* __restrict__ xb) {
  size_t i = ((size_t)blockIdx.x * 256 + threadIdx.x) * 4;
  float4 v = *reinterpret_cast<const float4*>(x + i);
  ushort4 o;
  o.x = f2bf(v.x); o.y = f2bf(v.y); o.z = f2bf(v.z); o.w = f2bf(v.w);
  *reinterpret_cast<ushort4*>(xb + i) = o;
}

// ------- kernel 2: W[e][i][o] fp32 -> Wbt[e][o][i] bf16 (transpose) -------
__global__ void cvt_w(const float* __restrict__ W, u16* __restrict__ wbt) {
  __shared__ u16 t[64][72];
  const int e  = blockIdx.z;
  const int i0 = blockIdx.x * 64;
  const int o0 = blockIdx.y * 64;
  const int tid = threadIdx.x;
  const int c  = (tid & 15) * 4;
  const int r_ = tid >> 4;
  const float* src = W + ((size_t)e << 20);
#pragma unroll
  for (int p = 0; p < 4; ++p) {
    int r = r_ + p * 16;
    float4 v = *reinterpret_cast<const float4*>(src + (size_t)(i0 + r) * 1024 + o0 + c);
    t[r][c + 0] = f2bf(v.x); t[r][c + 1] = f2bf(v.y);
    t[r][c + 2] = f2bf(v.z); t[r][c + 3] = f2bf(v.w);
  }
  __syncthreads();
  u16* dst = wbt + ((size_t)e << 20);
#pragma unroll
  for (int p = 0; p < 4; ++p) {
    int orow = r_ + p * 16;
    ushort4 u;
    u.x = t[c + 0][orow]; u.y = t[c + 1][orow];
    u.z = t[c + 2][orow]; u.w = t[c + 3][orow];
    *reinterpret_cast<ushort4*>(dst + (size_t)(o0 + orow) * 1024 + i0 + c) = u;
  }
}

// ---------------- kernel 3: Horner GEMM, r10 schedule + A-local XCD map ---
// BM=BN=256 BK=64, 512 thr = 8 waves (2M x 4N), wave 128x64, acc 128 VGPR.
// r10 free-running tile (best measured: 240us / 52.5% MfmaUtil):
//   top: F0(8)+F1(4) reads + 8 GLDS (t+1, other parity)
//   LGKM(4)->F0 | F2 under P0 | LGKM(8)->F1 | F3 under P1 |
//   LGKM(4)->F2 | P2 | LGKM(0)->F3 | P3 | VM0 | barrier | [rescale 7x]
// NEW: (a) unroll x2 -> compile-time parity bases (kills per-tile VALU addr
// recompute); (b) XCD map 8 b0 x 4 n0 per XCD -> A slices (4MB/XCD) stay
// L2-resident across the 8 expert revisits (FETCH was 547MB from A misses).
// LDS (u16 elems): A dbuf @0,@16384; B dbuf @32768,@49152; rl @65536 (4096).
__global__ __launch_bounds__(512, 2)
void zgemm(const u16* __restrict__ xb, const u16* __restrict__ wbt,
           const float* __restrict__ wts, const float* __restrict__ bias,
           float* __restrict__ y) {
  __shared__ u16 sm[69632];
  char* smb = (char*)sm;
  float* rl = (float*)(sm + 65536);          // byte 131072

  const int tid = threadIdx.x;
  const int l   = tid & 63;
  const int w   = tid >> 6;
  const int wm  = w >> 2;                    // 0..1
  const int wn  = w & 3;                     // 0..3
  const int x8  = blockIdx.x & 7;            // XCD
  const int jj  = blockIdx.x >> 3;           // 0..31
  const int b0  = ((x8 << 3) + (jj >> 2)) << 8;  // 8 A-slices per XCD (4MB, L2)
  const int n0  = (jj & 3) << 8;                 // 4 B-panels per XCD

  // ---- ratio table rl[e][256]: e<7 -> w'_e/w'_{e+1}; rl[7] = w'_7
#pragma unroll
  for (int i = 0; i < 4; ++i) {
    const int flat = tid + i * 512;
    const int e = flat & 7, r = flat >> 3;
    const float* wr = wts + (size_t)(b0 + r) * EXPERTS;
    float we = fmaxf(wr[e], 1e-20f);
    float rr = (e < 7) ? we / fmaxf(wr[e + 1], 1e-20f) : we;
    rl[e * 256 + r] = rr;
  }

  // ---- staging geometry (pre-swizzled global source, linear GLDS dest)
  const int rbl   = (w << 3) + (l >> 3);
  const int chunk = ((l & 7) ^ (l >> 3)) << 3;
  const u16* pAg = xb  + (size_t)(b0 + rbl) * IN_DIM + chunk;
  const u16* pBg = wbt + (size_t)(n0 + rbl) * 1024 + chunk;

  // ---- fragment read keys
  const int l15  = l & 15;
  const int kb0  = (((l >> 4) << 4)) ^ ((l & 7) << 4);   // kf0; kf1 = ^64
  const int arow = (wm * 128 + l15) * 128;               // + m*2048
  const int brow = (wn * 64 + l15) * 128;                // + n*2048
  const int wlo  = (wm << 9) + ((l >> 4) << 4);          // rl byte off + m*64

  f32x4 acc[8][4];
#pragma unroll
  for (int m = 0; m < 8; ++m)
#pragma unroll
    for (int n = 0; n < 4; ++n) acc[m][n] = (f32x4){0.f, 0.f, 0.f, 0.f};

#define STG_A(q, dstE, kv)                                                 \
  GLDS16(pAg + (size_t)((q) * 64) * 1024 + (size_t)(kv) * 64,              \
         sm + (dstE) + (q) * 4096 + (w << 9))
#define STG_B(q, dstE, off)                                                \
  GLDS16(pBg + (off) + (size_t)((q) * 64) * 1024,                          \
         sm + (dstE) + (q) * 4096 + (w << 9))

#define MM(AV, BV, MB)                                                     \
  __builtin_amdgcn_s_setprio(1);                                           \
  _Pragma("unroll")                                                        \
  for (int m = 0; m < 4; ++m)                                              \
    _Pragma("unroll")                                                      \
    for (int n = 0; n < 4; ++n)                                            \
      acc[(MB) + m][n] = MFMA_BF16(AV[m], BV[n], acc[(MB) + m][n], 0, 0, 0); \
  __builtin_amdgcn_s_setprio(0);

  // ---- prologue: tile 0 -> parity-0; drain; publish
  STG_A(0, 0, 0); STG_A(1, 0, 0); STG_A(2, 0, 0); STG_A(3, 0, 0);
  STG_B(0, 32768, 0); STG_B(1, 32768, 0); STG_B(2, 32768, 0); STG_B(3, 32768, 0);
  VM0;
  LGKM(0);                                   // rl ds_writes drained
  __builtin_amdgcn_s_barrier();

// BODY: TT tile-idx expr (parity known); ARB/BRB read bases (bytes);
// AWE/BWE stage bases (elems).  Exact r10 per-tile sequence.
#define BODY(TT, ARB, BRB, AWE, BWE)                                       \
  {                                                                        \
    const int tn  = ((TT) + 1) & 127;                                      \
    const int e1  = tn >> 4, k1 = tn & 15;                                 \
    const size_t boffg = (size_t)e1 * 1048576 + (size_t)k1 * 64;           \
    bf16x8 a0[4], b0v[4], a1[4], a2v[4], b1v[4], a3[4];                    \
    _Pragma("unroll")                                                      \
    for (int m = 0; m < 4; ++m)                                            \
      a0[m] = *(const bf16x8*)(smb + (ARB) + arow + m * 2048 + kb0);       \
    _Pragma("unroll")                                                      \
    for (int n = 0; n < 4; ++n)                                            \
      b0v[n] = *(const bf16x8*)(smb + (BRB) + brow + n * 2048 + kb0);      \
    _Pragma("unroll")                                                      \
    for (int m = 0; m < 4; ++m)                                            \
      a1[m] = *(const bf16x8*)(smb + (ARB) + arow + (m + 4) * 2048 + kb0); \
    STG_A(0, AWE, k1); STG_A(1, AWE, k1); STG_A(2, AWE, k1); STG_A(3, AWE, k1); \
    STG_B(0, BWE, boffg); STG_B(1, BWE, boffg);                            \
    STG_B(2, BWE, boffg); STG_B(3, BWE, boffg);                            \
    LGKM(4); SB0;                          /* F0 done (F1 in flight) */    \
    _Pragma("unroll")                                                      \
    for (int m = 0; m < 4; ++m)                                            \
      a2v[m] = *(const bf16x8*)(smb + (ARB) + arow + m * 2048 + (kb0 ^ 64)); \
    _Pragma("unroll")                                                      \
    for (int n = 0; n < 4; ++n)                                            \
      b1v[n] = *(const bf16x8*)(smb + (BRB) + brow + n * 2048 + (kb0 ^ 64)); \
    MM(a0, b0v, 0)                         /* P0 */                        \
    LGKM(8); SB0;                          /* F1 done */                   \
    _Pragma("unroll")                                                      \
    for (int m = 0; m < 4; ++m)                                            \
      a3[m] = *(const bf16x8*)(smb + (ARB) + arow + (m + 4) * 2048 + (kb0 ^ 64)); \
    MM(a1, b0v, 4)                         /* P1 */                        \
    LGKM(4); SB0;                          /* F2 done */                   \
    MM(a2v, b1v, 0)                        /* P2 */                        \
    LGKM(0); SB0;                          /* F3 done */                   \
    MM(a3, b1v, 4)                         /* P3 */                        \
    VM0;                                   /* t+1 staging landed */        \
    __builtin_amdgcn_s_barrier();          /* publish (only barrier) */    \
    if (((TT) & 15) == 15 && (TT) != 127) {                                \
      const int e = (TT) >> 4;                                             \
      f32x4 rv[8];                                                         \
      _Pragma("unroll")                                                    \
      for (int m = 0; m < 8; ++m)                                          \
        rv[m] = *(const f32x4*)(smb + 131072 + e * 1024 + wlo + m * 64);   \
      LGKM(0); SB0;                                                        \
      _Pragma("unroll")                                                    \
      for (int m = 0; m < 8; ++m)                                          \
        _Pragma("unroll")                                                  \
        for (int n = 0; n < 4; ++n) acc[m][n] *= rv[m];                    \
    }                                                                      \
  }

#pragma unroll 1
  for (int t = 0; t < 128; t += 2) {
    BODY(t,     0,     65536, 16384, 49152)   // read parity0, stage parity1
    BODY(t + 1, 32768, 98304, 0,     32768)   // read parity1, stage parity0
  }
  VM0; LGKM(0);

  // ---- epilogue: y = w'_7 * acc + sum_e w_e * bias_e
  float bv[4][8];
#pragma unroll
  for (int n = 0; n < 4; ++n) {
    const int c = n0 + wn * 64 + n * 16 + l15;
#pragma unroll
    for (int ee = 0; ee < 8; ++ee) bv[n][ee] = bias[ee * OUT_DIM + c];
  }
#pragma unroll
  for (int m = 0; m < 8; ++m) {
    const f32x4 rv7 = *(const f32x4*)(smb + 131072 + 7 * 1024 + wlo + m * 64);
    const int r0 = b0 + wm * 128 + m * 16 + ((l >> 4) << 2);
#pragma unroll
    for (int j = 0; j < 4; ++j) {
      const float* wr = wts + (size_t)(r0 + j) * EXPERTS;
      float w8[8];
#pragma unroll
      for (int ee = 0; ee < 8; ++ee) w8[ee] = wr[ee];
#pragma unroll
      for (int n = 0; n < 4; ++n) {
        const int c = n0 + wn * 64 + n * 16 + l15;
        float v = acc[m][n][j] * rv7[j];
#pragma unroll
        for (int ee = 0; ee < 8; ++ee) v += w8[ee] * bv[n][ee];
        y[(size_t)(r0 + j) * OUT_DIM + c] = v;
      }
    }
  }
}

extern "C" void kernel_launch(void* const* d_in, const int* in_sizes, int n_in,
                              void* d_out, int out_size, void* d_ws, size_t ws_size,
                              hipStream_t stream) {
  const float* x    = (const float*)d_in[0];
  const float* wts  = (const float*)d_in[1];
  const float* W    = (const float*)d_in[2];
  const float* bias = (const float*)d_in[3];
  float* y = (float*)d_out;

  const size_t xb_elems = (size_t)BATCH * IN_DIM;                 // 32 MB bf16
  const size_t wb_elems = (size_t)EXPERTS * IN_DIM * OUT_DIM;     // 16 MB bf16
  if (ws_size < (xb_elems + wb_elems) * sizeof(u16)) return;      // loud failure
  u16* xb  = (u16*)d_ws;
  u16* wbt = xb + xb_elems;

  cvt_x<<<(BATCH * IN_DIM) / (4 * 256), 256, 0, stream>>>(x, xb);
  cvt_w<<<dim3(IN_DIM / 64, OUT_DIM / 64, EXPERTS), 256, 0, stream>>>(W, wbt);
  zgemm<<<dim3(256), 512, 0, stream>>>(xb, wbt, wts, bias, y);
}